// Round 2
// baseline (198.370 us; speedup 1.0000x reference)
//
#include <hip/hip_runtime.h>
#include <stdint.h>

#define BATCH 4096
#define DDIM  768
#define EDIM  512
#define NSPLIT 16
#define LOG2E 1.44269504088896340736f

using short8  = __attribute__((ext_vector_type(8))) short;
using float4v = __attribute__((ext_vector_type(4))) float;

__device__ __forceinline__ unsigned short f2bf(float x) {
    union { float f; uint32_t u; } v; v.f = x;
    uint32_t u = v.u;
    u += 0x7FFFu + ((u >> 16) & 1u);   // round-to-nearest-even
    return (unsigned short)(u >> 16);
}
__device__ __forceinline__ float bf2f(unsigned short h) {
    union { uint32_t u; float f; } v; v.u = ((uint32_t)h) << 16;
    return v.f;
}

// async global->LDS, 16B per lane; LDS side must be wave-uniform base + lane*16
__device__ __forceinline__ void gl2lds16(const void* g, void* l) {
    __builtin_amdgcn_global_load_lds(
        (const __attribute__((address_space(1))) void*)g,
        (__attribute__((address_space(3))) void*)l, 16, 0, 0);
}

// ---------------- fp32 -> bf16 for images & texts in one launch ----------------
__global__ void cvt2(const float* __restrict__ a, const float* __restrict__ b,
                     unsigned short* __restrict__ oa, unsigned short* __restrict__ ob) {
    int i = blockIdx.x * 256 + threadIdx.x;
    const float* in = blockIdx.y ? b : a;
    unsigned short* out = blockIdx.y ? ob : oa;
    float4 v = ((const float4*)in)[i];
    ushort4 o;
    o.x = f2bf(v.x); o.y = f2bf(v.y); o.z = f2bf(v.z); o.w = f2bf(v.w);
    ((ushort4*)out)[i] = o;
}

// ---------------- both W (K x N fp32) -> Wt (N x K bf16) in one launch ----------------
__global__ void transpose2(const float* __restrict__ Wa, const float* __restrict__ Wb,
                           unsigned short* __restrict__ Ta, unsigned short* __restrict__ Tb) {
    const float* W = blockIdx.z ? Wb : Wa;
    unsigned short* Wt = blockIdx.z ? Tb : Ta;
    __shared__ float tile[32][33];
    int n0 = blockIdx.x * 32, k0 = blockIdx.y * 32;
    int tid = threadIdx.x;
    for (int p = 0; p < 4; ++p) {
        int e = tid + p * 256; int lr = e >> 5, lc = e & 31;
        tile[lc][lr] = W[(size_t)(k0 + lr) * EDIM + n0 + lc];
    }
    __syncthreads();
    for (int p = 0; p < 4; ++p) {
        int e = tid + p * 256; int lr = e >> 5, lc = e & 31;
        Wt[(size_t)(n0 + lr) * DDIM + k0 + lc] = f2bf(tile[lr][lc]);
    }
}

// ---------------- NT GEMM: C[4096x512] f32 = A[4096x768] bf16 @ B[512x768]^T ----------------
// tile 64x64, grid (64,8)=512 blocks (2/CU); async staging + XOR bank swizzle
__global__ __launch_bounds__(256) void gemm_nt(const unsigned short* __restrict__ A,
                                               const unsigned short* __restrict__ Bm,
                                               float* __restrict__ C) {
    __shared__ __align__(16) unsigned short As[64 * 32];
    __shared__ __align__(16) unsigned short Bs[64 * 32];
    int tid = threadIdx.x;
    int wave = tid >> 6, lane = tid & 63;
    int q = lane >> 4, r = lane & 15;
    int m0 = blockIdx.x * 64, n0 = blockIdx.y * 64;
    int srow = tid >> 2, skp = tid & 3;
    int skp2 = skp ^ ((srow >> 1) & 3);               // swizzled k-quarter (global side)
    const unsigned short* ga = &A[(size_t)(m0 + srow) * DDIM + skp2 * 8];
    const unsigned short* gb = &Bm[(size_t)(n0 + srow) * DDIM + skp2 * 8];
    unsigned short* la = &As[tid * 8];
    unsigned short* lb = &Bs[tid * 8];
    int sw = (r >> 1) & 3;                            // reader swizzle
    float4v acc[4];
    for (int t = 0; t < 4; ++t) acc[t] = (float4v){0.f, 0.f, 0.f, 0.f};
    for (int kc = 0; kc < DDIM / 32; ++kc) {
        __syncthreads();
        gl2lds16(ga + kc * 32, la);
        gl2lds16(gb + kc * 32, lb);
        __syncthreads();
        short8 af = *(const short8*)&As[(wave * 16 + r) * 32 + (q ^ sw) * 8];
        for (int t = 0; t < 4; ++t) {
            short8 bf = *(const short8*)&Bs[(t * 16 + r) * 32 + (q ^ sw) * 8];
            acc[t] = __builtin_amdgcn_mfma_f32_16x16x32_bf16(af, bf, acc[t], 0, 0, 0);
        }
    }
    for (int t = 0; t < 4; ++t)
        for (int g = 0; g < 4; ++g)
            C[(size_t)(m0 + wave * 16 + q * 4 + g) * EDIM + n0 + t * 16 + r] = acc[t][g];
}

// ---------------- row L2-normalize: f32[4096x512] -> bf16[4096x512] ----------------
__global__ void norm_rows(const float* __restrict__ Cin, unsigned short* __restrict__ outn) {
    int wave = threadIdx.x >> 6, lane = threadIdx.x & 63;
    int row = blockIdx.x * 4 + wave;
    const float4* rp = (const float4*)&Cin[(size_t)row * 512];
    float4 v0 = rp[lane * 2], v1 = rp[lane * 2 + 1];
    float s = v0.x*v0.x + v0.y*v0.y + v0.z*v0.z + v0.w*v0.w
            + v1.x*v1.x + v1.y*v1.y + v1.z*v1.z + v1.w*v1.w;
    for (int off = 1; off < 64; off <<= 1) s += __shfl_xor(s, off);
    float rn = rsqrtf(s);
    union { unsigned short us[8]; uint4 u4; } o;
    o.us[0] = f2bf(v0.x * rn); o.us[1] = f2bf(v0.y * rn);
    o.us[2] = f2bf(v0.z * rn); o.us[3] = f2bf(v0.w * rn);
    o.us[4] = f2bf(v1.x * rn); o.us[5] = f2bf(v1.y * rn);
    o.us[6] = f2bf(v1.z * rn); o.us[7] = f2bf(v1.w * rn);
    *(uint4*)&outn[(size_t)row * 512 + lane * 8] = o.u4;
}

// ---------------- raw dot: tvals[i] = dot(img_n[i], txt_n[labels[i]]) (no alpha) ----------------
__global__ void tdot(const unsigned short* __restrict__ img, const unsigned short* __restrict__ txt,
                     const int* __restrict__ labels, float* __restrict__ tout) {
    int wave = threadIdx.x >> 6, lane = threadIdx.x & 63;
    int row = blockIdx.x * 4 + wave;
    int lab = labels[row];
    union { unsigned short us[8]; uint4 u4; } a, b;
    a.u4 = *(const uint4*)&img[(size_t)row * 512 + lane * 8];
    b.u4 = *(const uint4*)&txt[(size_t)lab * 512 + lane * 8];
    float s = 0.f;
    for (int j = 0; j < 8; ++j) s += bf2f(a.us[j]) * bf2f(b.us[j]);
    for (int off = 1; off < 64; off <<= 1) s += __shfl_xor(s, off);
    if (lane == 0) tout[row] = s;
}

// ---------------- fused logits + fixed-max softmax sums + masked denom ----------------
// grid (64, 16); block 256 = 4 waves; wave: 16 rows x 256 cols (split)
// Fixed max M = alpha (|logit| <= alpha since inputs are L2-normalized) -> no online
// rescale, no per-slice cross-lane reductions.
__global__ __launch_bounds__(256, 4) void flash_pass(
    const unsigned short* __restrict__ img, const unsigned short* __restrict__ txt,
    const int* __restrict__ labels, const float* __restrict__ tvals,
    const float* __restrict__ ls,
    float* __restrict__ lP, float* __restrict__ dP) {
    __shared__ __align__(16) unsigned short Bs[8 * 64 * 32];  // 32 KB: [k32-chunk][col][k8]
    int tid = threadIdx.x;
    int wave = tid >> 6, lane = tid & 63;
    int q = lane >> 4, r = lane & 15;
    int row0 = blockIdx.x * 64 + wave * 16;
    int split = blockIdx.y;
    float alpha = expf(ls[0]);
    float c1 = alpha * LOG2E;          // p = exp2(c1*(cos - 1)) = e^{s - M}

    int srow = tid >> 2, skp = tid & 3;
    int skp2 = skp ^ ((srow >> 1) & 3);
    int sw = (r >> 1) & 3;

    // A fragments (16 rows x K=512) register-resident
    short8 af[16];
    for (int kc = 0; kc < 16; ++kc)
        af[kc] = *(const short8*)&img[(size_t)(row0 + r) * 512 + kc * 32 + q * 8];

    int labr[4]; float tr[4];
    for (int g = 0; g < 4; ++g) {
        int rw = row0 + q * 4 + g;
        labr[g] = labels[rw];
        tr[g] = tvals[rw];
    }
    float l[4] = {0.f, 0.f, 0.f, 0.f}, d[4] = {0.f, 0.f, 0.f, 0.f};

    for (int ct = 0; ct < 4; ++ct) {
        int colbase = split * 256 + ct * 64;
        const unsigned short* gB = &txt[(size_t)(colbase + srow) * 512 + skp2 * 8];
        float4v acc[4];
        for (int t = 0; t < 4; ++t) acc[t] = (float4v){0.f, 0.f, 0.f, 0.f};
        for (int h = 0; h < 2; ++h) {
            __syncthreads();
            for (int i = 0; i < 8; ++i)
                gl2lds16(gB + h * 256 + i * 32, &Bs[i * 2048 + tid * 8]);
            __syncthreads();
            for (int kc = 0; kc < 8; ++kc) {
                short8 a = af[h * 8 + kc];
                for (int t = 0; t < 4; ++t) {
                    short8 bf = *(const short8*)&Bs[(kc * 64 + t * 16 + r) * 32 + (q ^ sw) * 8];
                    acc[t] = __builtin_amdgcn_mfma_f32_16x16x32_bf16(a, bf, acc[t], 0, 0, 0);
                }
            }
        }
        // per-lane accumulation only — no cross-lane work per slice
        for (int t = 0; t < 4; ++t) {
            int lc = labels[colbase + t * 16 + r];
            for (int g = 0; g < 4; ++g) {
                float a = acc[t][g];
                float p = exp2f(fmaf(a, c1, -c1));
                l[g] += p;
                d[g] += ((a > tr[g]) && (lc != labr[g])) ? p : 0.f;
            }
        }
    }
    // final reduction over the 16 lanes sharing each row
    for (int g = 0; g < 4; ++g) {
        float lv = l[g], dv = d[g];
        for (int off = 1; off < 16; off <<= 1) {
            lv += __shfl_xor(lv, off);
            dv += __shfl_xor(dv, off);
        }
        if (r == 0) {
            int rw = row0 + q * 4 + g;
            lP[(size_t)rw * NSPLIT + split] = lv;
            dP[(size_t)rw * NSPLIT + split] = dv;
        }
    }
}

// ---------------- merge splits + per-row losses + global sum (atomic) ----------------
__global__ void combine(const float* __restrict__ lP, const float* __restrict__ dP,
                        const float* __restrict__ tvals, const float* __restrict__ ls,
                        float* __restrict__ out) {
    int row = blockIdx.x * 256 + threadIdx.x;
    float alpha = expf(ls[0]);
    float L = 0.f, D = 0.f;
    for (int s = 0; s < NSPLIT; ++s) {
        L += lP[(size_t)row * NSPLIT + s];
        D += dP[(size_t)row * NSPLIT + s];
    }
    float tm = alpha * (tvals[row] - 1.0f);   // t - M, with M = alpha
    float clip = logf(L) - tm;
    float py = expf(tm) / L;
    float cmp = (D > 0.f) ? py / (D / L + 1e-10f) : 0.f;
    float v = clip + cmp;
    for (int off = 1; off < 64; off <<= 1) v += __shfl_xor(v, off);
    __shared__ float w4[4];
    int wave = threadIdx.x >> 6, lane = threadIdx.x & 63;
    if (lane == 0) w4[wave] = v;
    __syncthreads();
    if (threadIdx.x == 0)
        atomicAdd(out, (w4[0] + w4[1] + w4[2] + w4[3]) * (1.0f / BATCH));
}

extern "C" void kernel_launch(void* const* d_in, const int* in_sizes, int n_in,
                              void* d_out, int out_size, void* d_ws, size_t ws_size,
                              hipStream_t stream) {
    const float* images = (const float*)d_in[0];
    const float* texts  = (const float*)d_in[1];
    const int*   labels = (const int*)d_in[2];
    const float* W_img  = (const float*)d_in[3];
    const float* W_txt  = (const float*)d_in[4];
    const float* lscale = (const float*)d_in[5];
    float* out = (float*)d_out;

    char* ws = (char*)d_ws;
    unsigned short* img_bf = (unsigned short*)(ws + 0);           // 6,291,456 B (dead after gemm#1)
    unsigned short* txt_bf = (unsigned short*)(ws + 6291456);     // 6,291,456 B (dead after gemm#2)
    unsigned short* wt_img = (unsigned short*)(ws + 12582912);    //   786,432 B
    unsigned short* wt_txt = (unsigned short*)(ws + 13369344);    //   786,432 B
    float*          proj   = (float*)(ws + 14155776);             // 8,388,608 B (reused)
    unsigned short* img_n  = (unsigned short*)(ws + 22544384);    // 4,194,304 B
    unsigned short* txt_n  = (unsigned short*)(ws + 26738688);    // 4,194,304 B
    // aliased over dead img_bf region (written only after both gemms):
    float*          lP     = (float*)(ws + 0);                    //   262,144 B
    float*          dP     = (float*)(ws + 262144);               //   262,144 B
    float*          tvals  = (float*)(ws + 524288);               //    16,384 B

    hipMemsetAsync(out, 0, sizeof(float), stream);
    cvt2<<<dim3(3072, 2), 256, 0, stream>>>(images, texts, img_bf, txt_bf);
    transpose2<<<dim3(EDIM / 32, DDIM / 32, 2), 256, 0, stream>>>(W_img, W_txt, wt_img, wt_txt);
    gemm_nt<<<dim3(BATCH / 64, EDIM / 64), 256, 0, stream>>>(img_bf, wt_img, proj);
    norm_rows<<<BATCH / 4, 256, 0, stream>>>(proj, img_n);
    gemm_nt<<<dim3(BATCH / 64, EDIM / 64), 256, 0, stream>>>(txt_bf, wt_txt, proj);
    norm_rows<<<BATCH / 4, 256, 0, stream>>>(proj, txt_n);
    tdot<<<BATCH / 4, 256, 0, stream>>>(img_n, txt_n, labels, tvals);
    flash_pass<<<dim3(BATCH / 64, NSPLIT), 256, 0, stream>>>(img_n, txt_n, labels, tvals, lscale,
                                                             lP, dP);
    combine<<<16, 256, 0, stream>>>(lP, dP, tvals, lscale, out);
}

// Round 3
// 132.527 us; speedup vs baseline: 1.4968x; 1.4968x over previous
//
#include <hip/hip_runtime.h>
#include <stdint.h>

#define BATCH 4096
#define DDIM  768
#define EDIM  512
#define NSPLIT 16
#define LOG2E 1.44269504088896340736f

using short8  = __attribute__((ext_vector_type(8))) short;
using float4v = __attribute__((ext_vector_type(4))) float;

__device__ __forceinline__ unsigned short f2bf(float x) {
    union { float f; uint32_t u; } v; v.f = x;
    uint32_t u = v.u;
    u += 0x7FFFu + ((u >> 16) & 1u);   // round-to-nearest-even
    return (unsigned short)(u >> 16);
}
__device__ __forceinline__ float bf2f(unsigned short h) {
    union { uint32_t u; float f; } v; v.u = ((uint32_t)h) << 16;
    return v.f;
}

// async global->LDS, 16B per lane; LDS dst must be wave-uniform base + lane*16
__device__ __forceinline__ void gl2lds16(const void* g, void* l) {
    __builtin_amdgcn_global_load_lds(
        (const __attribute__((address_space(1))) void*)g,
        (__attribute__((address_space(3))) void*)l, 16, 0, 0);
}

// ---------------- fp32 -> bf16 for images & texts in one launch ----------------
__global__ void cvt2(const float* __restrict__ a, const float* __restrict__ b,
                     unsigned short* __restrict__ oa, unsigned short* __restrict__ ob) {
    int i = blockIdx.x * 256 + threadIdx.x;
    const float* in = blockIdx.y ? b : a;
    unsigned short* out = blockIdx.y ? ob : oa;
    float4 v = ((const float4*)in)[i];
    ushort4 o;
    o.x = f2bf(v.x); o.y = f2bf(v.y); o.z = f2bf(v.z); o.w = f2bf(v.w);
    ((ushort4*)out)[i] = o;
}

// ---------------- both W (K x N fp32) -> Wt (N x K bf16) in one launch ----------------
__global__ void transpose2(const float* __restrict__ Wa, const float* __restrict__ Wb,
                           unsigned short* __restrict__ Ta, unsigned short* __restrict__ Tb) {
    const float* W = blockIdx.z ? Wb : Wa;
    unsigned short* Wt = blockIdx.z ? Tb : Ta;
    __shared__ float tile[32][33];
    int n0 = blockIdx.x * 32, k0 = blockIdx.y * 32;
    int tid = threadIdx.x;
    for (int p = 0; p < 4; ++p) {
        int e = tid + p * 256; int lr = e >> 5, lc = e & 31;
        tile[lc][lr] = W[(size_t)(k0 + lr) * EDIM + n0 + lc];
    }
    __syncthreads();
    for (int p = 0; p < 4; ++p) {
        int e = tid + p * 256; int lr = e >> 5, lc = e & 31;
        Wt[(size_t)(n0 + lr) * DDIM + k0 + lc] = f2bf(tile[lr][lc]);
    }
}

// ---------------- fused NT GEMM (both modalities): Cbf16[4096x512] = A @ W^T ----------------
// grid (32, 8, 2); block 256 = 4 waves; tile 128x64, wave = 32 rows x 64 cols (2 row-groups)
// BK=64 staged as two 32-k chunks, XOR bank swizzle (0 conflicts verified in R2)
__global__ __launch_bounds__(256) void gemm_nt(const unsigned short* __restrict__ Aimg,
                                               const unsigned short* __restrict__ Atxt,
                                               const unsigned short* __restrict__ Bimg,
                                               const unsigned short* __restrict__ Btxt,
                                               unsigned short* __restrict__ Cimg,
                                               unsigned short* __restrict__ Ctxt) {
    const unsigned short* A  = blockIdx.z ? Atxt : Aimg;
    const unsigned short* Bm = blockIdx.z ? Btxt : Bimg;
    unsigned short* C        = blockIdx.z ? Ctxt : Cimg;
    __shared__ __align__(16) unsigned short As[2 * 128 * 32];  // 16 KB
    __shared__ __align__(16) unsigned short Bs[2 * 64 * 32];   //  8 KB
    int tid = threadIdx.x;
    int wave = tid >> 6, lane = tid & 63;
    int q = lane >> 4, r = lane & 15;
    int m0 = blockIdx.x * 128, n0 = blockIdx.y * 64;
    int sw = (r >> 1) & 3;

    // per-thread staging sources (6 issues: 4 for As, 2 for Bs)
    const unsigned short* gsA[4];
    unsigned short* lsA[4];
    for (int i = 0; i < 4; ++i) {
        int u = i * 256 + tid;
        int kc2 = u >> 9, row = (u >> 2) & 127, kq = u & 3;
        int kq2 = kq ^ ((row >> 1) & 3);
        gsA[i] = &A[(size_t)(m0 + row) * DDIM + kc2 * 32 + kq2 * 8];
        lsA[i] = &As[u * 8];
    }
    const unsigned short* gsB[2];
    unsigned short* lsB[2];
    for (int i = 0; i < 2; ++i) {
        int u = i * 256 + tid;
        int kc2 = u >> 8, row = (u >> 2) & 63, kq = u & 3;
        int kq2 = kq ^ ((row >> 1) & 3);
        gsB[i] = &Bm[(size_t)(n0 + row) * DDIM + kc2 * 32 + kq2 * 8];
        lsB[i] = &Bs[u * 8];
    }

    float4v acc[2][4];
    for (int a = 0; a < 2; ++a)
        for (int t = 0; t < 4; ++t) acc[a][t] = (float4v){0.f, 0.f, 0.f, 0.f};

    for (int it = 0; it < DDIM / 64; ++it) {
        int k0 = it * 64;
        __syncthreads();
        for (int i = 0; i < 4; ++i) gl2lds16(gsA[i] + k0, lsA[i]);
        for (int i = 0; i < 2; ++i) gl2lds16(gsB[i] + k0, lsB[i]);
        __syncthreads();
        for (int kc2 = 0; kc2 < 2; ++kc2) {
            short8 a0 = *(const short8*)&As[kc2 * 4096 + (wave * 32 + r) * 32 + (q ^ sw) * 8];
            short8 a1 = *(const short8*)&As[kc2 * 4096 + (wave * 32 + 16 + r) * 32 + (q ^ sw) * 8];
            for (int t = 0; t < 4; ++t) {
                short8 b = *(const short8*)&Bs[kc2 * 2048 + (t * 16 + r) * 32 + (q ^ sw) * 8];
                acc[0][t] = __builtin_amdgcn_mfma_f32_16x16x32_bf16(a0, b, acc[0][t], 0, 0, 0);
                acc[1][t] = __builtin_amdgcn_mfma_f32_16x16x32_bf16(a1, b, acc[1][t], 0, 0, 0);
            }
        }
    }
    for (int rg = 0; rg < 2; ++rg)
        for (int t = 0; t < 4; ++t)
            for (int g = 0; g < 4; ++g)
                C[(size_t)(m0 + wave * 32 + rg * 16 + q * 4 + g) * EDIM + n0 + t * 16 + r] =
                    f2bf(acc[rg][t][g]);
}

// ---------------- in-place row L2-normalize of bf16 projections (both) ----------------
__global__ void norm_rows(unsigned short* __restrict__ Pa, unsigned short* __restrict__ Pb) {
    unsigned short* P = blockIdx.y ? Pb : Pa;
    int wave = threadIdx.x >> 6, lane = threadIdx.x & 63;
    int row = blockIdx.x * 4 + wave;
    unsigned short* p = &P[(size_t)row * 512 + lane * 8];
    union { unsigned short us[8]; uint4 u4; } v;
    v.u4 = *(const uint4*)p;
    float f[8], s = 0.f;
    for (int j = 0; j < 8; ++j) { f[j] = bf2f(v.us[j]); s += f[j] * f[j]; }
    for (int off = 1; off < 64; off <<= 1) s += __shfl_xor(s, off);
    float rn = rsqrtf(s);
    for (int j = 0; j < 8; ++j) v.us[j] = f2bf(f[j] * rn);
    *(uint4*)p = v.u4;
}

// ---------------- raw dot: tvals[i] = dot(img_n[i], txt_n[labels[i]]) ----------------
__global__ void tdot(const unsigned short* __restrict__ img, const unsigned short* __restrict__ txt,
                     const int* __restrict__ labels, float* __restrict__ tout) {
    int wave = threadIdx.x >> 6, lane = threadIdx.x & 63;
    int row = blockIdx.x * 4 + wave;
    int lab = labels[row];
    union { unsigned short us[8]; uint4 u4; } a, b;
    a.u4 = *(const uint4*)&img[(size_t)row * 512 + lane * 8];
    b.u4 = *(const uint4*)&txt[(size_t)lab * 512 + lane * 8];
    float s = 0.f;
    for (int j = 0; j < 8; ++j) s += bf2f(a.us[j]) * bf2f(b.us[j]);
    for (int off = 1; off < 64; off <<= 1) s += __shfl_xor(s, off);
    if (lane == 0) tout[row] = s;
}

// ---------------- fused logits + fixed-max softmax sums + masked denom ----------------
// grid (64, 16); block 256 = 4 waves; wave: 16 rows x 256 cols (split)
// Fixed max M = alpha (|logit| <= alpha, L2-normalized inputs) -> per-lane accumulation only.
// NOTE: no min-waves in launch_bounds — R2's (256,4) capped VGPR at 64 and spilled af[16].
__global__ __launch_bounds__(256) void flash_pass(
    const unsigned short* __restrict__ img, const unsigned short* __restrict__ txt,
    const int* __restrict__ labels, const float* __restrict__ tvals,
    const float* __restrict__ ls,
    float* __restrict__ lP, float* __restrict__ dP) {
    __shared__ __align__(16) unsigned short Bs[8 * 64 * 32];  // 32 KB
    int tid = threadIdx.x;
    int wave = tid >> 6, lane = tid & 63;
    int q = lane >> 4, r = lane & 15;
    int row0 = blockIdx.x * 64 + wave * 16;
    int split = blockIdx.y;
    float alpha = expf(ls[0]);
    float c1 = alpha * LOG2E;          // p = exp2(c1*(cos - 1)) = e^{s - M}

    int srow = tid >> 2, skp = tid & 3;
    int skp2 = skp ^ ((srow >> 1) & 3);
    int sw = (r >> 1) & 3;

    // A fragments (16 rows x K=512) register-resident: 64 VGPRs
    short8 af[16];
    for (int kc = 0; kc < 16; ++kc)
        af[kc] = *(const short8*)&img[(size_t)(row0 + r) * 512 + kc * 32 + q * 8];

    int labr[4]; float tr[4];
    for (int g = 0; g < 4; ++g) {
        int rw = row0 + q * 4 + g;
        labr[g] = labels[rw];
        tr[g] = tvals[rw];
    }
    float l[4] = {0.f, 0.f, 0.f, 0.f}, d[4] = {0.f, 0.f, 0.f, 0.f};

    for (int ct = 0; ct < 4; ++ct) {
        int colbase = split * 256 + ct * 64;
        const unsigned short* gB = &txt[(size_t)(colbase + srow) * 512 + skp2 * 8];
        float4v acc[4];
        for (int t = 0; t < 4; ++t) acc[t] = (float4v){0.f, 0.f, 0.f, 0.f};
        for (int h = 0; h < 2; ++h) {
            __syncthreads();
            for (int i = 0; i < 8; ++i)
                gl2lds16(gB + h * 256 + i * 32, &Bs[i * 2048 + tid * 8]);
            __syncthreads();
            for (int kc = 0; kc < 8; ++kc) {
                short8 a = af[h * 8 + kc];
                for (int t = 0; t < 4; ++t) {
                    short8 bf = *(const short8*)&Bs[(kc * 64 + t * 16 + r) * 32 + (q ^ sw) * 8];
                    acc[t] = __builtin_amdgcn_mfma_f32_16x16x32_bf16(a, bf, acc[t], 0, 0, 0);
                }
            }
        }
        for (int t = 0; t < 4; ++t) {
            int lc = labels[colbase + t * 16 + r];
            for (int g = 0; g < 4; ++g) {
                float a = acc[t][g];
                float p = exp2f(fmaf(a, c1, -c1));
                l[g] += p;
                d[g] += ((a > tr[g]) && (lc != labr[g])) ? p : 0.f;
            }
        }
    }
    for (int g = 0; g < 4; ++g) {
        float lv = l[g], dv = d[g];
        for (int off = 1; off < 16; off <<= 1) {
            lv += __shfl_xor(lv, off);
            dv += __shfl_xor(dv, off);
        }
        if (r == 0) {
            int rw = row0 + q * 4 + g;
            lP[(size_t)rw * NSPLIT + split] = lv;
            dP[(size_t)rw * NSPLIT + split] = dv;
        }
    }
}

// ---------------- merge splits + per-row losses + global sum (atomic) ----------------
__global__ void combine(const float* __restrict__ lP, const float* __restrict__ dP,
                        const float* __restrict__ tvals, const float* __restrict__ ls,
                        float* __restrict__ out) {
    int row = blockIdx.x * 256 + threadIdx.x;
    float alpha = expf(ls[0]);
    float L = 0.f, D = 0.f;
    for (int s = 0; s < NSPLIT; ++s) {
        L += lP[(size_t)row * NSPLIT + s];
        D += dP[(size_t)row * NSPLIT + s];
    }
    float tm = alpha * (tvals[row] - 1.0f);   // t - M, with M = alpha
    float clip = logf(L) - tm;
    float py = expf(tm) / L;
    float cmp = (D > 0.f) ? py / (D / L + 1e-10f) : 0.f;
    float v = clip + cmp;
    for (int off = 1; off < 64; off <<= 1) v += __shfl_xor(v, off);
    __shared__ float w4[4];
    int wave = threadIdx.x >> 6, lane = threadIdx.x & 63;
    if (lane == 0) w4[wave] = v;
    __syncthreads();
    if (threadIdx.x == 0)
        atomicAdd(out, (w4[0] + w4[1] + w4[2] + w4[3]) * (1.0f / BATCH));
}

extern "C" void kernel_launch(void* const* d_in, const int* in_sizes, int n_in,
                              void* d_out, int out_size, void* d_ws, size_t ws_size,
                              hipStream_t stream) {
    const float* images = (const float*)d_in[0];
    const float* texts  = (const float*)d_in[1];
    const int*   labels = (const int*)d_in[2];
    const float* W_img  = (const float*)d_in[3];
    const float* W_txt  = (const float*)d_in[4];
    const float* lscale = (const float*)d_in[5];
    float* out = (float*)d_out;

    char* ws = (char*)d_ws;
    unsigned short* img_bf = (unsigned short*)(ws + 0);           // 6,291,456 B
    unsigned short* txt_bf = (unsigned short*)(ws + 6291456);     // 6,291,456 B
    unsigned short* wt_img = (unsigned short*)(ws + 12582912);    //   786,432 B
    unsigned short* wt_txt = (unsigned short*)(ws + 13369344);    //   786,432 B
    unsigned short* proj_i = (unsigned short*)(ws + 14155776);    // 4,194,304 B (bf16 img_n)
    unsigned short* proj_t = (unsigned short*)(ws + 18350080);    // 4,194,304 B (bf16 txt_n)
    // aliased over dead img_bf region (written only after the fused gemm):
    float*          lP     = (float*)(ws + 0);                    //   262,144 B
    float*          dP     = (float*)(ws + 262144);               //   262,144 B
    float*          tvals  = (float*)(ws + 524288);               //    16,384 B

    hipMemsetAsync(out, 0, sizeof(float), stream);
    cvt2<<<dim3(3072, 2), 256, 0, stream>>>(images, texts, img_bf, txt_bf);
    transpose2<<<dim3(EDIM / 32, DDIM / 32, 2), 256, 0, stream>>>(W_img, W_txt, wt_img, wt_txt);
    gemm_nt<<<dim3(BATCH / 128, EDIM / 64, 2), 256, 0, stream>>>(img_bf, txt_bf, wt_img, wt_txt,
                                                                 proj_i, proj_t);
    norm_rows<<<dim3(BATCH / 4, 2), 256, 0, stream>>>(proj_i, proj_t);
    tdot<<<BATCH / 4, 256, 0, stream>>>(proj_i, proj_t, labels, tvals);
    flash_pass<<<dim3(BATCH / 64, NSPLIT), 256, 0, stream>>>(proj_i, proj_t, labels, tvals, lscale,
                                                             lP, dP);
    combine<<<16, 256, 0, stream>>>(lP, dP, tvals, lscale, out);
}